// Round 1
// baseline (60.316 us; speedup 1.0000x reference)
//
#include <hip/hip_runtime.h>
#include <hip/hip_bf16.h>
#include <math.h>

// Problem constants (match reference)
#define B 8
#define L 2048
#define H 2048
#define NA 8
#define NEG_INF (-1e30f)

#define HCHUNKS 32
#define HC_SZ (H / HCHUNKS)   // 64

__device__ __forceinline__ float sigf(float t) {
    return 1.0f / (1.0f + __expf(-t));
}

// Kernel 1: partial Wy[b, hc, x] = sum_{h in chunk hc} y[b,h] * weight[h,x] * sigmoid(wa[a_b,h,x])
// grid: (B*2, HCHUNKS), block 256. Each thread handles 4 consecutive x (float4).
__global__ __launch_bounds__(256) void k_wy_partial(
    const float* __restrict__ y, const int* __restrict__ actions,
    const float* __restrict__ weight, const float* __restrict__ wa,
    float* __restrict__ partial)
{
    const int bx = blockIdx.x;            // b*2 + xtile
    const int hc = blockIdx.y;            // 0..HCHUNKS-1
    const int b  = bx >> 1;
    const int x0 = (bx & 1) * 1024 + threadIdx.x * 4;
    const int a  = actions[b];
    const int h0 = hc * HC_SZ;

    const float* __restrict__ yb     = y + b * H;
    const float* __restrict__ wbase  = weight + (size_t)h0 * H + x0;
    const float* __restrict__ wabase = wa + ((size_t)a * H + h0) * H + x0;

    float4 acc = make_float4(0.f, 0.f, 0.f, 0.f);
    #pragma unroll 4
    for (int i = 0; i < HC_SZ; ++i) {
        const float  yv = yb[h0 + i];
        const float4 w4 = *(const float4*)(wbase  + (size_t)i * H);
        const float4 a4 = *(const float4*)(wabase + (size_t)i * H);
        acc.x += yv * w4.x * sigf(a4.x);
        acc.y += yv * w4.y * sigf(a4.y);
        acc.z += yv * w4.z * sigf(a4.z);
        acc.w += yv * w4.w * sigf(a4.w);
    }
    *(float4*)(partial + ((size_t)(b * HCHUNKS + hc) * H) + x0) = acc;
}

// Kernel 2: Wy[b,x] = sum_hc partial[b,hc,x] + bias[x]*sigmoid(ba[a_b,x])
// grid: 16 blocks x 256 threads, each thread 4 x.
__global__ __launch_bounds__(256) void k_wy_reduce(
    const float* __restrict__ partial, const float* __restrict__ bias,
    const float* __restrict__ ba, const int* __restrict__ actions,
    float* __restrict__ Wy)
{
    const int idx = blockIdx.x * 256 + threadIdx.x;    // 0..B*H/4-1
    const int b   = idx / (H / 4);
    const int x0  = (idx % (H / 4)) * 4;
    const int a   = actions[b];

    float4 s = make_float4(0.f, 0.f, 0.f, 0.f);
    const float* __restrict__ p = partial + (size_t)b * HCHUNKS * H + x0;
    #pragma unroll 8
    for (int c = 0; c < HCHUNKS; ++c) {
        const float4 v = *(const float4*)(p + (size_t)c * H);
        s.x += v.x; s.y += v.y; s.z += v.z; s.w += v.w;
    }
    const float4 bi  = *(const float4*)(bias + x0);
    const float4 bav = *(const float4*)(ba + (size_t)a * H + x0);
    s.x += bi.x * sigf(bav.x);
    s.y += bi.y * sigf(bav.y);
    s.z += bi.z * sigf(bav.z);
    s.w += bi.w * sigf(bav.w);
    *(float4*)(Wy + (size_t)b * H + x0) = s;
}

// Kernel 3: xWy[b,l] = sum_h x[b,l,h] * Wy[b,h]  (+mask). One wave (64 lanes) per row.
// grid: B*L/4 blocks x 256 threads (4 waves/block).
__global__ __launch_bounds__(256) void k_xwy(
    const float* __restrict__ x, const float* __restrict__ Wy,
    const unsigned char* __restrict__ mask, float* __restrict__ xWy)
{
    const int wave = threadIdx.x >> 6;
    const int lane = threadIdx.x & 63;
    const int row  = blockIdx.x * 4 + wave;  // 0..B*L-1
    const int b    = row >> 11;              // /L

    const float* __restrict__ xb = x + (size_t)row * H;
    const float* __restrict__ wy = Wy + (size_t)b * H;

    float acc = 0.f;
    #pragma unroll
    for (int j = 0; j < H / 256; ++j) {      // 8 iters
        const int off = j * 256 + lane * 4;
        const float4 xv = *(const float4*)(xb + off);
        const float4 wv = *(const float4*)(wy + off);
        acc += xv.x * wv.x + xv.y * wv.y + xv.z * wv.z + xv.w * wv.w;
    }
    #pragma unroll
    for (int s = 32; s; s >>= 1) acc += __shfl_xor(acc, s, 64);
    if (lane == 0) xWy[row] = mask[row] ? NEG_INF : acc;
}

// Kernel 4: softmax over L per batch row. grid: B blocks x 256 threads (8 elems/thread).
__global__ __launch_bounds__(256) void k_softmax(
    const float* __restrict__ xWy, float* __restrict__ out)
{
    const int b    = blockIdx.x;
    const int tid  = threadIdx.x;
    const int wave = tid >> 6;
    const int lane = tid & 63;
    const float* __restrict__ v = xWy + (size_t)b * L;

    float vals[L / 256];
    float m = -INFINITY;
    #pragma unroll
    for (int j = 0; j < L / 256; ++j) {
        vals[j] = v[tid + j * 256];
        m = fmaxf(m, vals[j]);
    }
    #pragma unroll
    for (int s = 32; s; s >>= 1) m = fmaxf(m, __shfl_xor(m, s, 64));

    __shared__ float redm[4];
    if (lane == 0) redm[wave] = m;
    __syncthreads();
    m = fmaxf(fmaxf(redm[0], redm[1]), fmaxf(redm[2], redm[3]));

    float sum = 0.f;
    #pragma unroll
    for (int j = 0; j < L / 256; ++j) {
        vals[j] = __expf(vals[j] - m);
        sum += vals[j];
    }
    #pragma unroll
    for (int s = 32; s; s >>= 1) sum += __shfl_xor(sum, s, 64);

    __shared__ float reds[4];
    if (lane == 0) reds[wave] = sum;
    __syncthreads();
    sum = reds[0] + reds[1] + reds[2] + reds[3];

    const float inv = 1.0f / sum;
    #pragma unroll
    for (int j = 0; j < L / 256; ++j)
        out[(size_t)b * L + tid + j * 256] = vals[j] * inv;
}

extern "C" void kernel_launch(void* const* d_in, const int* in_sizes, int n_in,
                              void* d_out, int out_size, void* d_ws, size_t ws_size,
                              hipStream_t stream) {
    const float*         x       = (const float*)d_in[0];
    const float*         y       = (const float*)d_in[1];
    const unsigned char* mask    = (const unsigned char*)d_in[2];
    const int*           actions = (const int*)d_in[3];
    const float*         weight  = (const float*)d_in[4];
    const float*         bias    = (const float*)d_in[5];
    const float*         wa      = (const float*)d_in[6];
    const float*         ba      = (const float*)d_in[7];
    float*               out     = (float*)d_out;

    float* ws      = (float*)d_ws;
    float* partial = ws;                               // B*HCHUNKS*H floats = 2 MiB
    float* Wy      = partial + (size_t)B * HCHUNKS * H; // B*H floats
    float* xWy     = Wy + (size_t)B * H;                // B*L floats

    dim3 g1(B * 2, HCHUNKS);
    k_wy_partial<<<g1, 256, 0, stream>>>(y, actions, weight, wa, partial);
    k_wy_reduce<<<(B * H / 4) / 256, 256, 0, stream>>>(partial, bias, ba, actions, Wy);
    k_xwy<<<B * L / 4, 256, 0, stream>>>(x, Wy, mask, xWy);
    k_softmax<<<B, 256, 0, stream>>>(xWy, out);
}